// Round 6
// baseline (371.433 us; speedup 1.0000x reference)
//
#include <hip/hip_runtime.h>
#include <math.h>

#define M0 128
#define M1 64
#define M2 32
#define DIMN 480      // 128 + 3*64 + 5*32
#define MSGC 64
#define NBLK 3
#define RBFD 32
#define NT 2048       // r-table resolution
#define TCHUNK 32     // t-values per k_rtab block
#define NNP 16        // nodes per k_proj block
#define FCUT 5.0f

typedef unsigned int   u32;
typedef unsigned short u16;

__device__ __forceinline__ u16 f2bf(float f) {
    u32 u = __float_as_uint(f);
    u32 r = (u + 0x7fffu + ((u >> 16) & 1u)) >> 16;
    return (u16)r;
}
__device__ __forceinline__ float bf_lo(u32 v) { return __uint_as_float(v << 16); }
__device__ __forceinline__ float bf_hi(u32 v) { return __uint_as_float(v & 0xffff0000u); }
__device__ __forceinline__ float bf2f(u32 us) { return __uint_as_float(us << 16); }

// 48-byte dst-sorted edge record: [src,ti,fr,fc][sh1..4][sh5..8]
struct __align__(16) ERec {
    int   src;
    int   ti;
    float fr;
    float fc;
    float sh[8];
};

// ---------- zero counts ----------
__global__ void k_zero(int* __restrict__ p, int n) {
    int i = blockIdx.x * blockDim.x + threadIdx.x;
    if (i < n) p[i] = 0;
}

// ---------- pass 1: count edges per dst ----------
__global__ void k_count(const int* __restrict__ dst, int* __restrict__ counts, int E) {
    int e = blockIdx.x * blockDim.x + threadIdx.x;
    if (e >= E) return;
    atomicAdd(&counts[dst[e]], 1);
}

// ---------- exclusive prefix scan (single block) ----------
__global__ void k_scan(const int* __restrict__ counts, int* __restrict__ offs,
                       int* __restrict__ cursor, int n) {
    __shared__ int buf[4096];
    for (int i = threadIdx.x; i < n; i += blockDim.x) buf[i] = counts[i];
    __syncthreads();
    for (int d = 1; d < n; d <<= 1) {
        int vals[4];
        int k = 0;
        for (int i = threadIdx.x; i < n; i += blockDim.x, ++k)
            vals[k] = (i >= d) ? buf[i - d] : 0;
        __syncthreads();
        k = 0;
        for (int i = threadIdx.x; i < n; i += blockDim.x, ++k)
            buf[i] += vals[k];
        __syncthreads();
    }
    for (int i = threadIdx.x; i < n; i += blockDim.x) {
        int excl = (i == 0) ? 0 : buf[i - 1];
        offs[i] = excl;
        cursor[i] = excl;
    }
    if (threadIdx.x == 0) offs[n] = buf[n - 1];
}

// ---------- pass 2: edge features scattered into dst order ----------
__global__ void k_build(const float* __restrict__ ew, const float* __restrict__ ev,
                        const int* __restrict__ src, const int* __restrict__ dst,
                        int* __restrict__ cursor, ERec* __restrict__ rec, int E) {
    int e = blockIdx.x * blockDim.x + threadIdx.x;
    if (e >= E) return;
    float len = ew[e];
    float inv = 1.0f / fmaxf(len, 1e-8f);
    float x = ev[e * 3 + 0] * inv;
    float y = ev[e * 3 + 1] * inv;
    float z = ev[e * 3 + 2] * inv;
    const float s3 = 1.7320508075688772f, s5 = 2.23606797749979f, s15 = 3.872983346207417f;
    ERec r;
    r.src = src[e];
    float u = fminf(len, FCUT) * ((float)(NT - 1) / FCUT);
    int ti = (int)u;
    ti = min(ti, NT - 2);
    r.ti = ti;
    r.fr = u - (float)ti;
    float t = fminf(len / FCUT, 1.0f);
    r.fc = 0.5f * (cosf(3.14159265358979323846f * t) + 1.0f);
    r.sh[0] = s3 * x;
    r.sh[1] = s3 * y;
    r.sh[2] = s3 * z;
    r.sh[3] = s15 * x * y;
    r.sh[4] = s15 * y * z;
    r.sh[5] = 0.5f * s5 * (3.0f * z * z - 1.0f);
    r.sh[6] = s15 * x * z;
    r.sh[7] = 0.5f * s15 * (x * x - y * y);
    int p = atomicAdd(&cursor[dst[e]], 1);
    rec[p] = r;
}

// ---------- x init ----------
__global__ __launch_bounds__(128) void k_initx(const int* __restrict__ z,
                                               const float* __restrict__ mask,
                                               const float* __restrict__ zemb,
                                               const float* __restrict__ Win,
                                               float* __restrict__ x) {
    int n = blockIdx.x;
    __shared__ float zf[M0];
    int zi = z[n];
    for (int k = threadIdx.x; k < M0; k += blockDim.x) zf[k] = zemb[zi * M0 + k];
    __syncthreads();
    int j = threadIdx.x;
    float acc = 0.0f;
    for (int k = 0; k < M0; ++k) acc += zf[k] * Win[k * M0 + j];
    float fm = mask[n];
    x[(size_t)n * DIMN + j] = acc * fm;
    for (int t = M0 + j; t < DIMN; t += M0) x[(size_t)n * DIMN + t] = 0.0f;
}

// ---------- r-table (scalar fp32): rS[b][t][c] ----------
__global__ __launch_bounds__(256) void k_rtab(const float* __restrict__ rW1,
                                              const float* __restrict__ rb1,
                                              const float* __restrict__ rW2,
                                              const float* __restrict__ rb2,
                                              float* __restrict__ rS) {
    int blk = blockIdx.x;
    int b = blk / (NT / TCHUNK);
    int t0 = (blk % (NT / TCHUNK)) * TCHUNK;
    int tid = threadIdx.x;
    __shared__ float rbf_s[TCHUNK][RBFD];
    __shared__ float hh_s[64][TCHUNK];

    const float wdt = FCUT / (float)(RBFD - 1);
    for (int idx = tid; idx < TCHUNK * RBFD; idx += 256) {
        int tt = idx >> 5, k = idx & 31;
        float len = (float)(t0 + tt) * (FCUT / (float)(NT - 1));
        float d0 = (len - (float)k * wdt) / wdt;
        rbf_s[tt][k] = expf(-0.5f * d0 * d0);
    }
    __syncthreads();
    const float* W1 = rW1 + b * RBFD * 64;
    for (int idx = tid; idx < TCHUNK * 64; idx += 256) {
        int tt = idx >> 6, jj = idx & 63;
        float a = rb1[b * 64 + jj];
        #pragma unroll 8
        for (int k = 0; k < RBFD; ++k) a += rbf_s[tt][k] * W1[k * 64 + jj];
        hh_s[jj][tt] = a / (1.0f + expf(-a));
    }
    __syncthreads();
    if (tid < 192) {
        int c = tid;
        const float* W2 = rW2 + b * 64 * 192;
        float b2 = rb2[b * 192 + c];
        float* out = rS + (size_t)b * NT * 192;
        for (int g = 0; g < TCHUNK / 8; ++g) {
            float acc[8];
            #pragma unroll
            for (int u = 0; u < 8; ++u) acc[u] = b2;
            for (int k = 0; k < 64; ++k) {
                float w2 = W2[k * 192 + c];
                const float4* hp = (const float4*)&hh_s[k][g * 8];
                float4 h0 = hp[0], h1 = hp[1];
                acc[0] += h0.x * w2; acc[1] += h0.y * w2;
                acc[2] += h0.z * w2; acc[3] += h0.w * w2;
                acc[4] += h1.x * w2; acc[5] += h1.y * w2;
                acc[6] += h1.z * w2; acc[7] += h1.w * w2;
            }
            #pragma unroll
            for (int u = 0; u < 8; ++u) {
                int t = t0 + g * 8 + u;
                out[(size_t)t * 192 + c] = acc[u];
            }
        }
    }
}

// ---------- pack r-table: rP[idx] = bf16(rS[t]) | bf16(rS[t+1])<<16 ----------
__global__ void k_pack(const float* __restrict__ rS, u32* __restrict__ rP, int total) {
    int idx = blockIdx.x * blockDim.x + threadIdx.x;
    if (idx >= total) return;
    int t = (idx / 192) % NT;
    float lo = rS[idx];
    float hi = (t < NT - 1) ? rS[idx + 192] : lo;
    rP[idx] = (u32)f2bf(lo) | ((u32)f2bf(hi) << 16);
}

// ---------- node projection: P_bf = bf16(x[:, :128] @ Wp[b]), 16 nodes/block ----------
__global__ __launch_bounds__(192) void k_proj(const float* __restrict__ x,
                                              const float* __restrict__ Wp,
                                              u16* __restrict__ P) {
    int n0 = blockIdx.x * NNP;
    int j = threadIdx.x;
    __shared__ float xs[NNP][M0];
    for (int idx = j; idx < NNP * M0; idx += 192) {
        int n = idx >> 7, c = idx & 127;
        xs[n][c] = x[(size_t)(n0 + n) * DIMN + c];
    }
    __syncthreads();
    float acc[NNP];
    #pragma unroll
    for (int u = 0; u < NNP; ++u) acc[u] = 0.0f;
    for (int k = 0; k < M0; ++k) {
        float wv = Wp[k * 192 + j];
        #pragma unroll
        for (int u = 0; u < NNP; ++u) acc[u] += xs[u][k] * wv;
    }
    #pragma unroll
    for (int u = 0; u < NNP; ++u)
        P[(size_t)(n0 + u) * 192 + j] = f2bf(acc[u]);
}

// ---------- edge-parallel weight compute: wbuf[i][c] = bf16(P[src][c] * r_interp * fc) ----------
// One 192-thread block per dst-sorted edge slot. All random reads (rtab row, P row)
// happen here, latency hidden by 131072 independent blocks.
__global__ __launch_bounds__(192) void k_wcomp(const u16* __restrict__ P,
                                               const u32* __restrict__ rt,
                                               const ERec* __restrict__ rec,
                                               u16* __restrict__ wbuf) {
    int i = blockIdx.x;
    int c = threadIdx.x;
    const float4* RP = (const float4*)rec;
    float4 m = RP[3 * (size_t)i];
    int src = __float_as_int(m.x), ti = __float_as_int(m.y);
    float fr = m.z, fc = m.w;
    u32 r = rt[(size_t)ti * 192 + c];
    float lo = bf_lo(r);
    float rv = lo + fr * (bf_hi(r) - lo);
    float pv = bf2f(P[(size_t)src * 192 + c]);
    wbuf[(size_t)i * 192 + c] = f2bf(pv * rv * fc);
}

// ---------- per-node gather (pure streaming) + fused Wo output transform ----------
__global__ __launch_bounds__(128) void k_gather(const u16* __restrict__ wbuf,
                                                const ERec* __restrict__ rec,
                                                const int* __restrict__ offs,
                                                const float* __restrict__ Wo0,
                                                const float* __restrict__ Wo1,
                                                const float* __restrict__ Wo2,
                                                const float* __restrict__ res_scale, int b,
                                                float* __restrict__ x) {
    int n = blockIdx.x;
    int t = threadIdx.x;
    int w = t >> 6;
    int j = t & 63;
    int e0 = offs[n], e1 = offs[n + 1];
    int base = e0 + w;                 // stride 2 across the 2 waves
    int nIter = (e1 - base + 1) >> 1;

    float m0 = 0.0f;
    float m1a[3] = {0, 0, 0};
    float m2a[5] = {0, 0, 0, 0, 0};

    if (nIter > 0) {
        const float4* RP = (const float4*)rec;
        int i = base;
        // stage 0
        float4 S1 = RP[3 * (size_t)i + 1], S2 = RP[3 * (size_t)i + 2];
        const u16* wp = wbuf + (size_t)i * 192;
        u16 wa = wp[j], wb = wp[64 + j], wc = wp[128 + j];
        for (int k = 0; k < nIter; ++k) {
            int inext = base + ((k + 1) << 1);
            if (inext >= e1) inext = i;        // harmless reload on last iter
            float4 T1 = RP[3 * (size_t)inext + 1], T2 = RP[3 * (size_t)inext + 2];
            const u16* wq = wbuf + (size_t)inext * 192;
            u16 na = wq[j], nb = wq[64 + j], nc = wq[128 + j];
            // consume current
            float fa = bf2f(wa), fb = bf2f(wb), fcv = bf2f(wc);
            m0 += fa;
            m1a[0] += fb * S1.x;
            m1a[1] += fb * S1.y;
            m1a[2] += fb * S1.z;
            m2a[0] += fcv * S1.w;
            m2a[1] += fcv * S2.x;
            m2a[2] += fcv * S2.y;
            m2a[3] += fcv * S2.z;
            m2a[4] += fcv * S2.w;
            S1 = T1; S2 = T2; wa = na; wb = nb; wc = nc; i = inext;
        }
    }

    __shared__ float mbuf[2][576];
    mbuf[w][j] = m0;
    #pragma unroll
    for (int d = 0; d < 3; ++d) mbuf[w][64 + d * 64 + j] = m1a[d];
    #pragma unroll
    for (int d = 0; d < 5; ++d) mbuf[w][256 + d * 64 + j] = m2a[d];
    __syncthreads();
    for (int c = t; c < 576; c += 128) mbuf[0][c] += mbuf[1][c];
    __syncthreads();

    // fused output transform: x[n] += rs * (msum @ blockdiag(Wo))
    float rs = res_scale[b];
    float* xn = x + (size_t)n * DIMN;
    for (int o = t; o < DIMN; o += 128) {
        const float* W;
        int stride, mbase;
        if (o < M0) {
            W = Wo0 + o; stride = M0; mbase = 0;
        } else if (o < M0 + 3 * M1) {
            int q = o - M0, k = q / 3, d = q - 3 * k;
            W = Wo1 + k; stride = M1; mbase = 64 + d * 64;
        } else {
            int q = o - (M0 + 3 * M1), k = q / 5, d = q - 5 * k;
            W = Wo2 + k; stride = M2; mbase = 256 + d * 64;
        }
        float acc = 0.0f;
        #pragma unroll 8
        for (int c = 0; c < 64; ++c) acc += mbuf[0][mbase + c] * W[c * stride];
        xn[o] += rs * acc;
    }
}

// ---------- final irrep norm + mask ----------
__global__ __launch_bounds__(64) void k_norm(const float* __restrict__ x,
                                             const float* __restrict__ mask,
                                             float* __restrict__ out) {
    int n = blockIdx.x;
    int j = threadIdx.x;
    const float* xn = x + (size_t)n * DIMN;
    float s0 = 0, s1 = 0, s2 = 0;
    for (int c = j; c < 128; c += 64) { float v = xn[c]; s0 += v * v; }
    for (int c = j; c < 192; c += 64) { float v = xn[128 + c]; s1 += v * v; }
    for (int c = j; c < 160; c += 64) { float v = xn[320 + c]; s2 += v * v; }
    for (int d = 32; d > 0; d >>= 1) {
        s0 += __shfl_down(s0, d);
        s1 += __shfl_down(s1, d);
        s2 += __shfl_down(s2, d);
    }
    __shared__ float inv0, inv1, inv2;
    if (j == 0) {
        inv0 = rsqrtf(s0 / (float)M0 + 1e-6f);
        inv1 = rsqrtf(s1 / (float)M1 + 1e-6f);
        inv2 = rsqrtf(s2 / (float)M2 + 1e-6f);
    }
    __syncthreads();
    float fm = mask[n];
    float* on = out + (size_t)n * DIMN;
    for (int c = j; c < 128; c += 64) on[c] = xn[c] * inv0 * fm;
    for (int c = j; c < 192; c += 64) on[128 + c] = xn[128 + c] * inv1 * fm;
    for (int c = j; c < 160; c += 64) on[320 + c] = xn[320 + c] * inv2 * fm;
}

extern "C" void kernel_launch(void* const* d_in, const int* in_sizes, int n_in,
                              void* d_out, int out_size, void* d_ws, size_t ws_size,
                              hipStream_t stream) {
    const int*   z    = (const int*)d_in[0];
    const float* mask = (const float*)d_in[1];
    const int*   esrc = (const int*)d_in[2];
    const int*   edst = (const int*)d_in[3];
    const float* ew   = (const float*)d_in[4];
    const float* ev   = (const float*)d_in[5];
    const float* zemb = (const float*)d_in[6];
    const float* Win  = (const float*)d_in[7];
    const float* Wp   = (const float*)d_in[8];
    const float* rW1  = (const float*)d_in[9];
    const float* rb1  = (const float*)d_in[10];
    const float* rW2  = (const float*)d_in[11];
    const float* rb2  = (const float*)d_in[12];
    const float* Wo0  = (const float*)d_in[13];
    const float* Wo1  = (const float*)d_in[14];
    const float* Wo2  = (const float*)d_in[15];
    const float* res  = (const float*)d_in[16];

    const int BN = in_sizes[0];      // 4096
    const int E  = in_sizes[2];      // 131072

    // ---- workspace carve ----
    char* w = (char*)d_ws;
    float* x    = (float*)w;  w += (size_t)BN * DIMN * 4;            // 7.86 MB
    u16*   P    = (u16*)w;    w += (size_t)BN * 192 * 2;             // 1.57 MB
    float* rS   = (float*)w;  w += (size_t)NBLK * NT * 192 * 4;      // 4.72 MB
    u32*   rP   = (u32*)w;    w += (size_t)NBLK * NT * 192 * 4;      // 4.72 MB
    ERec*  rec  = (ERec*)w;   w += (size_t)E * sizeof(ERec);         // 6.29 MB
    u16*   wbuf = (u16*)w;    w += (size_t)E * 192 * 2;              // 50.3 MB
    int* counts = (int*)w;   w += (size_t)BN * 4;
    int* offs   = (int*)w;   w += (size_t)(BN + 4) * 4;
    int* cursor = (int*)w;   w += (size_t)BN * 4;

    k_zero<<<(BN + 255) / 256, 256, 0, stream>>>(counts, BN);
    k_count<<<(E + 255) / 256, 256, 0, stream>>>(edst, counts, E);
    k_scan<<<1, 1024, 0, stream>>>(counts, offs, cursor, BN);
    k_build<<<(E + 255) / 256, 256, 0, stream>>>(ew, ev, esrc, edst, cursor, rec, E);
    k_initx<<<BN, 128, 0, stream>>>(z, mask, zemb, Win, x);
    k_rtab<<<NBLK * (NT / TCHUNK), 256, 0, stream>>>(rW1, rb1, rW2, rb2, rS);
    {
        int total = NBLK * NT * 192;
        k_pack<<<(total + 255) / 256, 256, 0, stream>>>(rS, rP, total);
    }

    for (int b = 0; b < NBLK; ++b) {
        k_proj<<<BN / NNP, 192, 0, stream>>>(x, Wp + (size_t)b * M0 * 192, P);
        k_wcomp<<<E, 192, 0, stream>>>(P, rP + (size_t)b * NT * 192, rec, wbuf);
        k_gather<<<BN, 128, 0, stream>>>(wbuf, rec, offs,
                                         Wo0 + (size_t)b * MSGC * M0,
                                         Wo1 + (size_t)b * MSGC * M1,
                                         Wo2 + (size_t)b * MSGC * M2,
                                         res, b, x);
    }

    k_norm<<<BN, 64, 0, stream>>>(x, mask, (float*)d_out);
}

// Round 7
// 225.214 us; speedup vs baseline: 1.6492x; 1.6492x over previous
//
#include <hip/hip_runtime.h>
#include <math.h>

#define M0 128
#define M1 64
#define M2 32
#define DIMN 480      // 128 + 3*64 + 5*32
#define MSGC 64
#define NBLK 3
#define RBFD 32
#define NT 2048       // r-table resolution
#define TCHUNK 32     // t-values per k_rtab block
#define NNP 16        // nodes per k_proj block
#define CHUNK 64      // edges staged per k_gather chunk
#define FCUT 5.0f

typedef unsigned int   u32;
typedef unsigned short u16;

__device__ __forceinline__ u16 f2bf(float f) {
    u32 u = __float_as_uint(f);
    u32 r = (u + 0x7fffu + ((u >> 16) & 1u)) >> 16;
    return (u16)r;
}
__device__ __forceinline__ float bf_lo(u32 v) { return __uint_as_float(v << 16); }
__device__ __forceinline__ float bf_hi(u32 v) { return __uint_as_float(v & 0xffff0000u); }
__device__ __forceinline__ float bf2f(u32 us) { return __uint_as_float(us << 16); }

// 48-byte dst-sorted edge record: [src,ti,fr,fc][sh1..4][sh5..8]
struct __align__(16) ERec {
    int   src;
    int   ti;
    float fr;
    float fc;
    float sh[8];
};

// ---------- zero counts ----------
__global__ void k_zero(int* __restrict__ p, int n) {
    int i = blockIdx.x * blockDim.x + threadIdx.x;
    if (i < n) p[i] = 0;
}

// ---------- pass 1: count edges per dst ----------
__global__ void k_count(const int* __restrict__ dst, int* __restrict__ counts, int E) {
    int e = blockIdx.x * blockDim.x + threadIdx.x;
    if (e >= E) return;
    atomicAdd(&counts[dst[e]], 1);
}

// ---------- exclusive scan, 4 elems/thread + Hillis-Steele on 1024 totals ----------
__global__ __launch_bounds__(1024) void k_scan(const int* __restrict__ counts,
                                               int* __restrict__ offs,
                                               int* __restrict__ cursor, int n) {
    __shared__ int ws[1024];
    int t = threadIdx.x;                 // n == 4096, 4 per thread
    int4 v = ((const int4*)counts)[t];
    int s0 = v.x, s1 = s0 + v.y, s2 = s1 + v.z, s3 = s2 + v.w;
    ws[t] = s3;
    __syncthreads();
    for (int d = 1; d < 1024; d <<= 1) {
        int val = (t >= d) ? ws[t - d] : 0;
        __syncthreads();
        ws[t] += val;
        __syncthreads();
    }
    int excl = (t == 0) ? 0 : ws[t - 1];
    int4 o;
    o.x = excl; o.y = excl + s0; o.z = excl + s1; o.w = excl + s2;
    ((int4*)offs)[t] = o;
    ((int4*)cursor)[t] = o;
    if (t == 1023) offs[n] = excl + s3;
}

// ---------- pass 2: edge features scattered into dst order ----------
__global__ void k_build(const float* __restrict__ ew, const float* __restrict__ ev,
                        const int* __restrict__ src, const int* __restrict__ dst,
                        int* __restrict__ cursor, ERec* __restrict__ rec, int E) {
    int e = blockIdx.x * blockDim.x + threadIdx.x;
    if (e >= E) return;
    float len = ew[e];
    float inv = 1.0f / fmaxf(len, 1e-8f);
    float x = ev[e * 3 + 0] * inv;
    float y = ev[e * 3 + 1] * inv;
    float z = ev[e * 3 + 2] * inv;
    const float s3 = 1.7320508075688772f, s5 = 2.23606797749979f, s15 = 3.872983346207417f;
    ERec r;
    r.src = src[e];
    float u = fminf(len, FCUT) * ((float)(NT - 1) / FCUT);
    int ti = (int)u;
    ti = min(ti, NT - 2);
    r.ti = ti;
    r.fr = u - (float)ti;
    float t = fminf(len / FCUT, 1.0f);
    r.fc = 0.5f * (cosf(3.14159265358979323846f * t) + 1.0f);
    r.sh[0] = s3 * x;
    r.sh[1] = s3 * y;
    r.sh[2] = s3 * z;
    r.sh[3] = s15 * x * y;
    r.sh[4] = s15 * y * z;
    r.sh[5] = 0.5f * s5 * (3.0f * z * z - 1.0f);
    r.sh[6] = s15 * x * z;
    r.sh[7] = 0.5f * s15 * (x * x - y * y);
    int p = atomicAdd(&cursor[dst[e]], 1);
    rec[p] = r;
}

// ---------- x init ----------
__global__ __launch_bounds__(128) void k_initx(const int* __restrict__ z,
                                               const float* __restrict__ mask,
                                               const float* __restrict__ zemb,
                                               const float* __restrict__ Win,
                                               float* __restrict__ x) {
    int n = blockIdx.x;
    __shared__ float zf[M0];
    int zi = z[n];
    for (int k = threadIdx.x; k < M0; k += blockDim.x) zf[k] = zemb[zi * M0 + k];
    __syncthreads();
    int j = threadIdx.x;
    float acc = 0.0f;
    for (int k = 0; k < M0; ++k) acc += zf[k] * Win[k * M0 + j];
    float fm = mask[n];
    x[(size_t)n * DIMN + j] = acc * fm;
    for (int t = M0 + j; t < DIMN; t += M0) x[(size_t)n * DIMN + t] = 0.0f;
}

// ---------- r-table (scalar fp32): rS[b][t][c] ----------
__global__ __launch_bounds__(256) void k_rtab(const float* __restrict__ rW1,
                                              const float* __restrict__ rb1,
                                              const float* __restrict__ rW2,
                                              const float* __restrict__ rb2,
                                              float* __restrict__ rS) {
    int blk = blockIdx.x;
    int b = blk / (NT / TCHUNK);
    int t0 = (blk % (NT / TCHUNK)) * TCHUNK;
    int tid = threadIdx.x;
    __shared__ float rbf_s[TCHUNK][RBFD];
    __shared__ float hh_s[64][TCHUNK];

    const float wdt = FCUT / (float)(RBFD - 1);
    for (int idx = tid; idx < TCHUNK * RBFD; idx += 256) {
        int tt = idx >> 5, k = idx & 31;
        float len = (float)(t0 + tt) * (FCUT / (float)(NT - 1));
        float d0 = (len - (float)k * wdt) / wdt;
        rbf_s[tt][k] = expf(-0.5f * d0 * d0);
    }
    __syncthreads();
    const float* W1 = rW1 + b * RBFD * 64;
    for (int idx = tid; idx < TCHUNK * 64; idx += 256) {
        int tt = idx >> 6, jj = idx & 63;
        float a = rb1[b * 64 + jj];
        #pragma unroll 8
        for (int k = 0; k < RBFD; ++k) a += rbf_s[tt][k] * W1[k * 64 + jj];
        hh_s[jj][tt] = a / (1.0f + expf(-a));
    }
    __syncthreads();
    if (tid < 192) {
        int c = tid;
        const float* W2 = rW2 + b * 64 * 192;
        float b2 = rb2[b * 192 + c];
        float* out = rS + (size_t)b * NT * 192;
        for (int g = 0; g < TCHUNK / 8; ++g) {
            float acc[8];
            #pragma unroll
            for (int u = 0; u < 8; ++u) acc[u] = b2;
            for (int k = 0; k < 64; ++k) {
                float w2 = W2[k * 192 + c];
                const float4* hp = (const float4*)&hh_s[k][g * 8];
                float4 h0 = hp[0], h1 = hp[1];
                acc[0] += h0.x * w2; acc[1] += h0.y * w2;
                acc[2] += h0.z * w2; acc[3] += h0.w * w2;
                acc[4] += h1.x * w2; acc[5] += h1.y * w2;
                acc[6] += h1.z * w2; acc[7] += h1.w * w2;
            }
            #pragma unroll
            for (int u = 0; u < 8; ++u) {
                int t = t0 + g * 8 + u;
                out[(size_t)t * 192 + c] = acc[u];
            }
        }
    }
}

// ---------- pack r-table: rP[idx] = bf16(rS[t]) | bf16(rS[t+1])<<16 ----------
__global__ void k_pack(const float* __restrict__ rS, u32* __restrict__ rP, int total) {
    int idx = blockIdx.x * blockDim.x + threadIdx.x;
    if (idx >= total) return;
    int t = (idx / 192) % NT;
    float lo = rS[idx];
    float hi = (t < NT - 1) ? rS[idx + 192] : lo;
    rP[idx] = (u32)f2bf(lo) | ((u32)f2bf(hi) << 16);
}

// ---------- node projection: P_bf = bf16(x[:, :128] @ Wp[b]), 16 nodes/block ----------
__global__ __launch_bounds__(192) void k_proj(const float* __restrict__ x,
                                              const float* __restrict__ Wp,
                                              u16* __restrict__ P) {
    int n0 = blockIdx.x * NNP;
    int j = threadIdx.x;
    __shared__ float xs[NNP][M0];
    for (int idx = j; idx < NNP * M0; idx += 192) {
        int n = idx >> 7, c = idx & 127;
        xs[n][c] = x[(size_t)(n0 + n) * DIMN + c];
    }
    __syncthreads();
    float acc[NNP];
    #pragma unroll
    for (int u = 0; u < NNP; ++u) acc[u] = 0.0f;
    for (int k = 0; k < M0; ++k) {
        float wv = Wp[k * 192 + j];
        #pragma unroll
        for (int u = 0; u < NNP; ++u) acc[u] += xs[u][k] * wv;
    }
    #pragma unroll
    for (int u = 0; u < NNP; ++u)
        P[(size_t)(n0 + u) * 192 + j] = f2bf(acc[u]);
}

// ---------- fused per-node gather + Wo transform (+ final norm on last block) ----------
// 4 waves/node. Edge metas staged in LDS (no dependent chain); each wave takes
// edges stride-4 with a 1-ahead pipeline of independent rtab/P loads.
__global__ __launch_bounds__(256) void k_gather(const u16* __restrict__ P,
                                                const u32* __restrict__ rt,
                                                const ERec* __restrict__ rec,
                                                const int* __restrict__ offs,
                                                const float* __restrict__ Wo0,
                                                const float* __restrict__ Wo1,
                                                const float* __restrict__ Wo2,
                                                const float* __restrict__ res_scale, int b,
                                                float* __restrict__ x,
                                                const float* __restrict__ mask,
                                                float* __restrict__ out) {
    int n = blockIdx.x;
    int t = threadIdx.x;
    int w = t >> 6;        // wave 0..3
    int j = t & 63;
    int e0 = offs[n], e1 = offs[n + 1];

    float m0 = 0.0f;
    float m1a[3] = {0, 0, 0};
    float m2a[5] = {0, 0, 0, 0, 0};

    __shared__ float4 smeta[CHUNK * 3];
    __shared__ float mbuf[4][576];
    __shared__ float xfin[DIMN];
    __shared__ float part[4][3];

    const float4* RP = (const float4*)rec;
    for (int c0 = e0; c0 < e1; c0 += CHUNK) {
        int cnt = min(CHUNK, e1 - c0);
        __syncthreads();
        for (int i = t; i < cnt * 3; i += 256) smeta[i] = RP[(size_t)3 * c0 + i];
        __syncthreads();

        int i = w;
        if (i < cnt) {
            // stage A for edge i
            float4 Am = smeta[i * 3], A1 = smeta[i * 3 + 1], A2 = smeta[i * 3 + 2];
            int asrc = __float_as_int(Am.x), ati = __float_as_int(Am.y);
            u32 ra = rt[(size_t)ati * 192 + j];
            u32 rb = rt[(size_t)ati * 192 + 64 + j];
            u32 rc = rt[(size_t)ati * 192 + 128 + j];
            u16 pa = P[(size_t)asrc * 192 + j];
            u16 pb = P[(size_t)asrc * 192 + 64 + j];
            u16 pc = P[(size_t)asrc * 192 + 128 + j];
            while (true) {
                int i2 = i + 4;
                bool h2 = i2 < cnt;
                float4 Bm, B1, B2;
                u32 ra2 = 0, rb2 = 0, rc2 = 0;
                u16 pa2 = 0, pb2 = 0, pc2 = 0;
                if (h2) {
                    Bm = smeta[i2 * 3]; B1 = smeta[i2 * 3 + 1]; B2 = smeta[i2 * 3 + 2];
                    int bsrc = __float_as_int(Bm.x), bti = __float_as_int(Bm.y);
                    ra2 = rt[(size_t)bti * 192 + j];
                    rb2 = rt[(size_t)bti * 192 + 64 + j];
                    rc2 = rt[(size_t)bti * 192 + 128 + j];
                    pa2 = P[(size_t)bsrc * 192 + j];
                    pb2 = P[(size_t)bsrc * 192 + 64 + j];
                    pc2 = P[(size_t)bsrc * 192 + 128 + j];
                }
                // consume stage A
                float fr = Am.z, fc = Am.w;
                float la = bf_lo(ra);
                float va = la + fr * (bf_hi(ra) - la);
                m0 += bf2f(pa) * va * fc;
                float lb = bf_lo(rb);
                float vb = lb + fr * (bf_hi(rb) - lb);
                float w1 = bf2f(pb) * vb * fc;
                m1a[0] += w1 * A1.x;
                m1a[1] += w1 * A1.y;
                m1a[2] += w1 * A1.z;
                float lc = bf_lo(rc);
                float vc = lc + fr * (bf_hi(rc) - lc);
                float w2 = bf2f(pc) * vc * fc;
                m2a[0] += w2 * A1.w;
                m2a[1] += w2 * A2.x;
                m2a[2] += w2 * A2.y;
                m2a[3] += w2 * A2.z;
                m2a[4] += w2 * A2.w;
                if (!h2) break;
                Am = Bm; A1 = B1; A2 = B2;
                ra = ra2; rb = rb2; rc = rc2;
                pa = pa2; pb = pb2; pc = pc2;
                i = i2;
            }
        }
    }

    mbuf[w][j] = m0;
    #pragma unroll
    for (int d = 0; d < 3; ++d) mbuf[w][64 + d * 64 + j] = m1a[d];
    #pragma unroll
    for (int d = 0; d < 5; ++d) mbuf[w][256 + d * 64 + j] = m2a[d];
    __syncthreads();
    for (int c = t; c < 576; c += 256)
        mbuf[0][c] += mbuf[1][c] + mbuf[2][c] + mbuf[3][c];
    __syncthreads();

    // fused output transform: upd[o] = x[n][o] + rs * (msum @ blockdiag(Wo))[o]
    float rs = res_scale[b];
    float* xn = x + (size_t)n * DIMN;
    for (int o = t; o < DIMN; o += 256) {
        const float* W;
        int stride, mbase;
        if (o < M0) {
            W = Wo0 + o; stride = M0; mbase = 0;
        } else if (o < M0 + 3 * M1) {
            int q = o - M0, k = q / 3, d = q - 3 * k;
            W = Wo1 + k; stride = M1; mbase = 64 + d * 64;
        } else {
            int q = o - (M0 + 3 * M1), k = q / 5, d = q - 5 * k;
            W = Wo2 + k; stride = M2; mbase = 256 + d * 64;
        }
        float acc = 0.0f;
        #pragma unroll 8
        for (int c = 0; c < 64; ++c) acc += mbuf[0][mbase + c] * W[c * stride];
        float upd = xn[o] + rs * acc;
        if (b < NBLK - 1) xn[o] = upd;
        else xfin[o] = upd;
    }

    if (b < NBLK - 1) return;

    // ---- final irrep norm + mask, fused into last block ----
    __syncthreads();
    float s0 = 0, s1 = 0, s2 = 0;
    for (int c = t; c < DIMN; c += 256) {
        float v = xfin[c];
        if (c < 128) s0 += v * v;
        else if (c < 320) s1 += v * v;
        else s2 += v * v;
    }
    for (int d = 32; d > 0; d >>= 1) {
        s0 += __shfl_down(s0, d);
        s1 += __shfl_down(s1, d);
        s2 += __shfl_down(s2, d);
    }
    if (j == 0) { part[w][0] = s0; part[w][1] = s1; part[w][2] = s2; }
    __syncthreads();
    if (t == 0) {
        float q0 = part[0][0] + part[1][0] + part[2][0] + part[3][0];
        float q1 = part[0][1] + part[1][1] + part[2][1] + part[3][1];
        float q2 = part[0][2] + part[1][2] + part[2][2] + part[3][2];
        part[0][0] = rsqrtf(q0 / (float)M0 + 1e-6f);
        part[0][1] = rsqrtf(q1 / (float)M1 + 1e-6f);
        part[0][2] = rsqrtf(q2 / (float)M2 + 1e-6f);
    }
    __syncthreads();
    float fm = mask[n];
    float i0 = part[0][0], i1 = part[0][1], i2 = part[0][2];
    float* on = out + (size_t)n * DIMN;
    for (int c = t; c < DIMN; c += 256) {
        float inv = (c < 128) ? i0 : (c < 320) ? i1 : i2;
        on[c] = xfin[c] * inv * fm;
    }
}

extern "C" void kernel_launch(void* const* d_in, const int* in_sizes, int n_in,
                              void* d_out, int out_size, void* d_ws, size_t ws_size,
                              hipStream_t stream) {
    const int*   z    = (const int*)d_in[0];
    const float* mask = (const float*)d_in[1];
    const int*   esrc = (const int*)d_in[2];
    const int*   edst = (const int*)d_in[3];
    const float* ew   = (const float*)d_in[4];
    const float* ev   = (const float*)d_in[5];
    const float* zemb = (const float*)d_in[6];
    const float* Win  = (const float*)d_in[7];
    const float* Wp   = (const float*)d_in[8];
    const float* rW1  = (const float*)d_in[9];
    const float* rb1  = (const float*)d_in[10];
    const float* rW2  = (const float*)d_in[11];
    const float* rb2  = (const float*)d_in[12];
    const float* Wo0  = (const float*)d_in[13];
    const float* Wo1  = (const float*)d_in[14];
    const float* Wo2  = (const float*)d_in[15];
    const float* res  = (const float*)d_in[16];

    const int BN = in_sizes[0];      // 4096
    const int E  = in_sizes[2];      // 131072

    // ---- workspace carve (16B-aligned pieces) ----
    char* w = (char*)d_ws;
    float* x    = (float*)w;  w += (size_t)BN * DIMN * 4;            // 7.86 MB
    u16*   P    = (u16*)w;    w += (size_t)BN * 192 * 2;             // 1.57 MB
    float* rS   = (float*)w;  w += (size_t)NBLK * NT * 192 * 4;      // 4.72 MB
    u32*   rP   = (u32*)w;    w += (size_t)NBLK * NT * 192 * 4;      // 4.72 MB
    ERec*  rec  = (ERec*)w;   w += (size_t)E * sizeof(ERec);         // 6.29 MB
    int* counts = (int*)w;   w += (size_t)BN * 4;
    int* offs   = (int*)w;   w += (size_t)(BN + 4) * 4;
    int* cursor = (int*)w;   w += (size_t)BN * 4;

    k_zero<<<(BN + 255) / 256, 256, 0, stream>>>(counts, BN);
    k_count<<<(E + 255) / 256, 256, 0, stream>>>(edst, counts, E);
    k_scan<<<1, 1024, 0, stream>>>(counts, offs, cursor, BN);
    k_build<<<(E + 255) / 256, 256, 0, stream>>>(ew, ev, esrc, edst, cursor, rec, E);
    k_initx<<<BN, 128, 0, stream>>>(z, mask, zemb, Win, x);
    k_rtab<<<NBLK * (NT / TCHUNK), 256, 0, stream>>>(rW1, rb1, rW2, rb2, rS);
    {
        int total = NBLK * NT * 192;
        k_pack<<<(total + 255) / 256, 256, 0, stream>>>(rS, rP, total);
    }

    for (int b = 0; b < NBLK; ++b) {
        k_proj<<<BN / NNP, 192, 0, stream>>>(x, Wp + (size_t)b * M0 * 192, P);
        k_gather<<<BN, 256, 0, stream>>>(P, rP + (size_t)b * NT * 192, rec, offs,
                                         Wo0 + (size_t)b * MSGC * M0,
                                         Wo1 + (size_t)b * MSGC * M1,
                                         Wo2 + (size_t)b * MSGC * M2,
                                         res, b, x, mask, (float*)d_out);
    }
}